// Round 3
// 477.598 us; speedup vs baseline: 1.0695x; 1.0695x over previous
//
#include <hip/hip_runtime.h>
#include <stdint.h>

typedef short short8 __attribute__((ext_vector_type(8)));
typedef float floatx16 __attribute__((ext_vector_type(16)));

// Problem constants
constexpr int CB = 8;      // batch
constexpr int CT = 8192;   // tokens
constexpr int CI = 512;    // in features (GEMM K-dim)
constexpr int CE = 16;     // experts
constexpr int CK = 1024;   // gathered rows per (b,e) (GEMM M-dim)
constexpr int CJ = 512;    // out features (GEMM N-dim)

// Device-global scratch (avoids any assumption about ws_size).
// xb: x converted to bf16, [B][T][I] packed 2 elems/word  -> 64 MB
// wb: W pre-packed bf16 tiles [E][nt=4][kt=8][kpq=8][jn=128][q=4] -> 8 MB
__device__ uint32_t g_xb[(size_t)CB * CT * CI / 2];
__device__ uint32_t g_wb[(size_t)CE * CI * CJ / 2];

__device__ __forceinline__ uint32_t f2bf(float f) {
    union { float f; uint32_t u; } c; c.f = f;
    return (c.u + 0x7fffu + ((c.u >> 16) & 1u)) >> 16;   // RNE to bf16 bits
}
__device__ __forceinline__ uint32_t pack2(float lo, float hi) {
    return f2bf(lo) | (f2bf(hi) << 16);
}

__device__ __forceinline__ void gl_lds16(const uint32_t* g, uint32_t* l) {
    __builtin_amdgcn_global_load_lds(
        (const __attribute__((address_space(1))) uint32_t*)g,
        (__attribute__((address_space(3))) uint32_t*)l,
        16, 0, 0);
}

// ---- prologue 1: x fp32 -> bf16 (plain row layout, 2 elems per word)
__global__ __launch_bounds__(256) void cvt_x(const float* __restrict__ x,
                                             uint32_t* __restrict__ xb) {
    size_t i = (size_t)blockIdx.x * 256 + threadIdx.x;   // one uint4 (8 floats)
    const float4* src = (const float4*)x;
    float4 a = src[2 * i], b = src[2 * i + 1];
    ((uint4*)xb)[i] = make_uint4(pack2(a.x, a.y), pack2(a.z, a.w),
                                 pack2(b.x, b.y), pack2(b.z, b.w));
}

// ---- prologue 2: W fp32 -> bf16, pre-packed into LDS tile order.
// Tile (e,nt,kt) is 16 KB: [kpq 0..7][jn 0..127][q 0..3] words,
// word (kpq,jn,q) = pack2(W[e][kt*64+kpq*8+2q][nt*128+jn], W[e][..+1][..])
__global__ __launch_bounds__(256) void cvt_w(const float* __restrict__ W,
                                             uint32_t* __restrict__ wb) {
    uint32_t tid = blockIdx.x * 256 + threadIdx.x;       // 524288 total
    int jn  = tid & 127;
    int kpq = (tid >> 7) & 7;
    int kt  = (tid >> 10) & 7;
    int nt  = (tid >> 13) & 3;
    int e   = tid >> 15;
    int n   = nt * 128 + jn;
    int k0  = kt * 64 + kpq * 8;
    const float* src = W + ((size_t)e * CI + k0) * CJ + n;
    uint4 o;
    o.x = pack2(src[0 * CJ], src[1 * CJ]);
    o.y = pack2(src[2 * CJ], src[3 * CJ]);
    o.z = pack2(src[4 * CJ], src[5 * CJ]);
    o.w = pack2(src[6 * CJ], src[7 * CJ]);
    ((uint4*)wb)[tid] = o;
}

// ---- main: 256 threads (4 waves), 128x128 output tile, BK=64, 8 K-iters.
// All staging via global_load_lds width=16. A tile XOR-swizzled (chunk ^= row&7,
// applied on the per-lane GLOBAL source so LDS dest stays linear — rule #21).
__global__ __launch_bounds__(256, 4) void eg_kernel(
    const uint32_t* __restrict__ xb, const int* __restrict__ Ind,
    const uint32_t* __restrict__ wb, float* __restrict__ out)
{
    __shared__ __align__(16) uint32_t As[128 * 32];  // 16 KB: [row 128][chunkswz 8][4w]
    __shared__ __align__(16) uint32_t Bs[32 * 128];  // 16 KB: [kpq 8][jn 128][q 4]
    __shared__ int s_idx[128];

    const int t = threadIdx.x;
    const int z = blockIdx.z;            // b*E + e
    const int e = z & (CE - 1);
    const int b = z >> 4;
    const int mtile = blockIdx.y;        // 0..7
    const int ntile = blockIdx.x;        // 0..3

    if (t < 128) s_idx[t] = Ind[z * CK + mtile * 128 + t];
    __syncthreads();

    const int ln = t & 63, wv = t >> 6;

    // A staging source: lane l stages 16B = global chunk ((l&7) ^ (l>>3)) of
    // gathered row (wv*32 + i*8 + (l>>3)); LDS dest is linear.
    const int sr = ln >> 3;                  // row within 8-row group (== row&7)
    const int gchunk = (ln & 7) ^ sr;        // pre-swizzled source chunk
    const uint32_t* xb_b = xb + (size_t)b * CT * 256;    // 256 words per token row
    const uint32_t* pA[4];
    #pragma unroll
    for (int i = 0; i < 4; ++i) {
        int r = wv * 32 + i * 8 + sr;
        pA[i] = xb_b + (size_t)s_idx[r] * 256 + gchunk * 4;
    }
    // B staging source: contiguous pre-packed tile, perfectly linear copy.
    const uint32_t* pB = wb + ((size_t)(e * 4 + ntile) * 8) * 4096 + wv * 1024 + ln * 4;

    // compute-side lane mapping
    const int wm = (wv >> 1) * 64, wn = (wv & 1) * 64;
    const int lrow = ln & 31;
    const int lh = ln >> 5;

    const floatx16 fz = {0.f,0.f,0.f,0.f,0.f,0.f,0.f,0.f,0.f,0.f,0.f,0.f,0.f,0.f,0.f,0.f};
    floatx16 acc[2][2] = {{fz, fz}, {fz, fz}};

    for (int kt = 0; kt < 8; ++kt) {
        // ---- stage A (128 rows x 64 k bf16 = 16 KB) + B (64 k x 128 n = 16 KB)
        #pragma unroll
        for (int i = 0; i < 4; ++i)
            gl_lds16(pA[i] + kt * 32, &As[wv * 1024 + i * 256]);
        #pragma unroll
        for (int i = 0; i < 4; ++i)
            gl_lds16(pB + (size_t)kt * 4096 + i * 256, &Bs[wv * 1024 + i * 256]);
        __syncthreads();

        // ---- four K=16 MFMA sub-steps
        #pragma unroll
        for (int s = 0; s < 4; ++s) {
            short8 af[2], bfr[2];
            #pragma unroll
            for (int mt = 0; mt < 2; ++mt) {
                const int row = wm + mt * 32 + lrow;
                const int ch = (s * 2 + lh) ^ (lrow & 7);   // undo the swizzle
                af[mt] = *(const short8*)&As[row * 32 + ch * 4];
            }
            #pragma unroll
            for (int nt = 0; nt < 2; ++nt) {
                const int jn = wn + nt * 32 + lrow;
                bfr[nt] = *(const short8*)&Bs[(s * 2 + lh) * 512 + jn * 4];
            }
            #pragma unroll
            for (int mt = 0; mt < 2; ++mt)
                #pragma unroll
                for (int nt = 0; nt < 2; ++nt)
                    acc[mt][nt] = __builtin_amdgcn_mfma_f32_32x32x16_bf16(
                        af[mt], bfr[nt], acc[mt][nt], 0, 0, 0);
        }
        __syncthreads();
    }

    // ---- epilogue: C/D layout col=lane&31, row=(r&3)+8*(r>>2)+4*(lane>>5)
    const size_t obase = (size_t)z * CK * CJ;
    #pragma unroll
    for (int mt = 0; mt < 2; ++mt) {
        const int gm0 = mtile * 128 + wm + mt * 32 + lh * 4;
        #pragma unroll
        for (int nt = 0; nt < 2; ++nt) {
            const int gn = ntile * 128 + wn + nt * 32 + lrow;
            #pragma unroll
            for (int r = 0; r < 16; ++r) {
                const int gm = gm0 + (r & 3) + 8 * (r >> 2);
                out[obase + (size_t)gm * CJ + gn] = acc[mt][nt][r];
            }
        }
    }
}

extern "C" void kernel_launch(void* const* d_in, const int* in_sizes, int n_in,
                              void* d_out, int out_size, void* d_ws, size_t ws_size,
                              hipStream_t stream) {
    const float* x   = (const float*)d_in[0];
    const int*   Ind = (const int*)d_in[1];
    const float* W   = (const float*)d_in[2];
    float* out = (float*)d_out;

    uint32_t* xb; hipGetSymbolAddress((void**)&xb, HIP_SYMBOL(g_xb));
    uint32_t* wb; hipGetSymbolAddress((void**)&wb, HIP_SYMBOL(g_wb));

    // prologues: convert once per call (inputs may be re-poisoned between calls)
    hipLaunchKernelGGL(cvt_x, dim3(CB * CT * CI / 8 / 256), dim3(256), 0, stream, x, xb);
    // one thread per uint4 (8 elems): CE*CI*CJ/8 = 524288 threads = 2048 blocks
    hipLaunchKernelGGL(cvt_w, dim3(CE * CI * CJ / 8 / 256), dim3(256), 0, stream, W, wb);

    dim3 grid(CJ / 128, CK / 128, CB * CE);   // (4, 8, 128) = 4096 blocks
    hipLaunchKernelGGL(eg_kernel, grid, dim3(256), 0, stream, xb, Ind, wb, out);
}

// Round 5
// 473.455 us; speedup vs baseline: 1.0789x; 1.0088x over previous
//
#include <hip/hip_runtime.h>
#include <stdint.h>

typedef short short8 __attribute__((ext_vector_type(8)));
typedef float floatx16 __attribute__((ext_vector_type(16)));

// Problem constants
constexpr int CB = 8;      // batch
constexpr int CT = 8192;   // tokens
constexpr int CI = 512;    // in features (GEMM K-dim)
constexpr int CE = 16;     // experts
constexpr int CK = 1024;   // gathered rows per (b,e) (GEMM M-dim)
constexpr int CJ = 512;    // out features (GEMM N-dim)

// Device-global scratch.
// xb: x converted to bf16, [B][T][I] packed 2 elems/word  -> 64 MB
// wb: W pre-packed bf16 tiles [E][nt=4][kt=8][kpq=8][jn=128][q=4] -> 8 MB
__device__ uint32_t g_xb[(size_t)CB * CT * CI / 2];
__device__ uint32_t g_wb[(size_t)CE * CI * CJ / 2];

__device__ __forceinline__ uint32_t f2bf(float f) {
    union { float f; uint32_t u; } c; c.f = f;
    return (c.u + 0x7fffu + ((c.u >> 16) & 1u)) >> 16;   // RNE to bf16 bits
}
__device__ __forceinline__ uint32_t pack2(float lo, float hi) {
    return f2bf(lo) | (f2bf(hi) << 16);
}

__device__ __forceinline__ void gl_lds16(const uint32_t* g, uint32_t* l) {
    __builtin_amdgcn_global_load_lds(
        (const __attribute__((address_space(1))) uint32_t*)g,
        (__attribute__((address_space(3))) uint32_t*)l,
        16, 0, 0);
}

// ---- fused prologue: one launch converts x and W.
// blocks [0, XBLK): x fp32 -> bf16 (row layout, 2 elems/word, one uint4/thread)
// blocks [XBLK, XBLK+WBLK): W fp32 -> bf16 pre-packed LDS tile order:
//   tile (e,nt,kt) = [kpq 0..7][jn 0..127][q 0..3] words,
//   word (kpq,jn,q) = pack2(W[e][kt*64+kpq*8+2q][nt*128+jn], W[e][..+1][..])
constexpr int XBLK = CB * CT * CI / 8 / 256;   // 16384
constexpr int WBLK = CE * CI * CJ / 8 / 256;   // 2048
__global__ __launch_bounds__(256) void cvt_xw(
    const float* __restrict__ x, uint32_t* __restrict__ xb,
    const float* __restrict__ W, uint32_t* __restrict__ wb)
{
    const int bid = blockIdx.x;
    if (bid < XBLK) {
        size_t i = (size_t)bid * 256 + threadIdx.x;      // one uint4 (8 floats)
        const float4* src = (const float4*)x;
        float4 a = src[2 * i], b = src[2 * i + 1];
        ((uint4*)xb)[i] = make_uint4(pack2(a.x, a.y), pack2(a.z, a.w),
                                     pack2(b.x, b.y), pack2(b.z, b.w));
    } else {
        uint32_t tid = (uint32_t)(bid - XBLK) * 256 + threadIdx.x;  // 524288 total
        int jn  = tid & 127;
        int kpq = (tid >> 7) & 7;
        int kt  = (tid >> 10) & 7;
        int nt  = (tid >> 13) & 3;
        int e   = tid >> 15;
        int n   = nt * 128 + jn;
        int k0  = kt * 64 + kpq * 8;
        const float* src = W + ((size_t)e * CI + k0) * CJ + n;
        uint4 o;
        o.x = pack2(src[0 * CJ], src[1 * CJ]);
        o.y = pack2(src[2 * CJ], src[3 * CJ]);
        o.z = pack2(src[4 * CJ], src[5 * CJ]);
        o.w = pack2(src[6 * CJ], src[7 * CJ]);
        ((uint4*)wb)[tid] = o;
    }
}

// ---- staging: 16 KB A tile (128 rows x 64 k bf16) + 16 KB B tile per kt.
__device__ __forceinline__ void stage_tiles(const uint32_t* const* pA, const uint32_t* pB,
                                            int kt, uint32_t* As, uint32_t* Bs, int wv) {
    #pragma unroll
    for (int i = 0; i < 4; ++i)
        gl_lds16(pA[i] + kt * 32, &As[wv * 1024 + i * 256]);
    #pragma unroll
    for (int i = 0; i < 4; ++i)
        gl_lds16(pB + (size_t)kt * 4096 + i * 256, &Bs[wv * 1024 + i * 256]);
}

// ---- compute: four K=16 MFMA sub-steps on one staged K-tile.
__device__ __forceinline__ void compute_tile(const uint32_t* As, const uint32_t* Bs,
                                             int wm, int wn, int lrow, int lh,
                                             floatx16 acc[2][2]) {
    #pragma unroll
    for (int s = 0; s < 4; ++s) {
        short8 af[2], bfr[2];
        #pragma unroll
        for (int mt = 0; mt < 2; ++mt) {
            const int row = wm + mt * 32 + lrow;
            const int ch = (s * 2 + lh) ^ (lrow & 7);   // undo the A swizzle
            af[mt] = *(const short8*)&As[row * 32 + ch * 4];
        }
        #pragma unroll
        for (int nt = 0; nt < 2; ++nt) {
            const int jn = wn + nt * 32 + lrow;
            bfr[nt] = *(const short8*)&Bs[(s * 2 + lh) * 512 + jn * 4];
        }
        #pragma unroll
        for (int mt = 0; mt < 2; ++mt)
            #pragma unroll
            for (int nt = 0; nt < 2; ++nt)
                acc[mt][nt] = __builtin_amdgcn_mfma_f32_32x32x16_bf16(
                    af[mt], bfr[nt], acc[mt][nt], 0, 0, 0);
    }
}

// ---- main: 256 threads (4 waves), 128x128 tile, BK=64, 8 K-tiles,
// prefetched double-buffer 2-phase: STAGE(next) issued BEFORE compute(cur),
// single drain+barrier per tile (catalog T3-minimum). Buffer parity is
// statically unrolled (distinct As0/As1) so alias analysis keeps the
// ds_reads free of a serializing vmcnt wait.
__global__ __launch_bounds__(256, 2) void eg_kernel(
    const uint32_t* __restrict__ xb, const int* __restrict__ Ind,
    const uint32_t* __restrict__ wb, float* __restrict__ out)
{
    __shared__ __align__(16) uint32_t As0[128 * 32], As1[128 * 32];  // 2 x 16 KB
    __shared__ __align__(16) uint32_t Bs0[32 * 128], Bs1[32 * 128];  // 2 x 16 KB
    __shared__ int s_idx[128];

    const int t = threadIdx.x;
    const int z = blockIdx.z;            // b*E + e
    const int e = z & (CE - 1);
    const int b = z >> 4;
    const int mtile = blockIdx.y;        // 0..7
    const int ntile = blockIdx.x;        // 0..3

    if (t < 128) s_idx[t] = Ind[z * CK + mtile * 128 + t];
    __syncthreads();

    const int ln = t & 63, wv = t >> 6;

    // A staging source: lane l stages 16B = global chunk ((l&7) ^ (l>>3)) of
    // gathered row (wv*32 + i*8 + (l>>3)); LDS dest linear (rule #21).
    const int sr = ln >> 3;
    const int gchunk = (ln & 7) ^ sr;
    const uint32_t* xb_b = xb + (size_t)b * CT * 256;    // 256 words per token row
    const uint32_t* pA[4];
    #pragma unroll
    for (int i = 0; i < 4; ++i) {
        int r = wv * 32 + i * 8 + sr;
        pA[i] = xb_b + (size_t)s_idx[r] * 256 + gchunk * 4;
    }
    // B staging source: contiguous pre-packed tile, linear copy.
    const uint32_t* pB = wb + ((size_t)(e * 4 + ntile) * 8) * 4096 + wv * 1024 + ln * 4;

    // compute-side lane mapping
    const int wm = (wv >> 1) * 64, wn = (wv & 1) * 64;
    const int lrow = ln & 31;
    const int lh = ln >> 5;

    const floatx16 fz = {0.f,0.f,0.f,0.f,0.f,0.f,0.f,0.f,0.f,0.f,0.f,0.f,0.f,0.f,0.f,0.f};
    floatx16 acc[2][2] = {{fz, fz}, {fz, fz}};

    stage_tiles(pA, pB, 0, As0, Bs0, wv);
    __syncthreads();                      // compiler drains vmcnt(0) here
    #pragma unroll
    for (int ktp = 0; ktp < 4; ++ktp) {
        stage_tiles(pA, pB, 2 * ktp + 1, As1, Bs1, wv);   // prefetch odd tile
        compute_tile(As0, Bs0, wm, wn, lrow, lh, acc);
        __syncthreads();                  // drain: As1/Bs1 now valid
        if (ktp < 3)
            stage_tiles(pA, pB, 2 * ktp + 2, As0, Bs0, wv); // prefetch even tile
        compute_tile(As1, Bs1, wm, wn, lrow, lh, acc);
        __syncthreads();
    }

    // ---- epilogue: C/D layout col=lane&31, row=(r&3)+8*(r>>2)+4*(lane>>5)
    const size_t obase = (size_t)z * CK * CJ;
    #pragma unroll
    for (int mt = 0; mt < 2; ++mt) {
        const int gm0 = mtile * 128 + wm + mt * 32 + lh * 4;
        #pragma unroll
        for (int nt = 0; nt < 2; ++nt) {
            const int gn = ntile * 128 + wn + nt * 32 + lrow;
            #pragma unroll
            for (int r = 0; r < 16; ++r) {
                const int gm = gm0 + (r & 3) + 8 * (r >> 2);
                out[obase + (size_t)gm * CJ + gn] = acc[mt][nt][r];
            }
        }
    }
}

extern "C" void kernel_launch(void* const* d_in, const int* in_sizes, int n_in,
                              void* d_out, int out_size, void* d_ws, size_t ws_size,
                              hipStream_t stream) {
    const float* x   = (const float*)d_in[0];
    const int*   Ind = (const int*)d_in[1];
    const float* W   = (const float*)d_in[2];
    float* out = (float*)d_out;

    uint32_t* xb; hipGetSymbolAddress((void**)&xb, HIP_SYMBOL(g_xb));
    uint32_t* wb; hipGetSymbolAddress((void**)&wb, HIP_SYMBOL(g_wb));

    // fused prologue: convert once per call (inputs may be re-poisoned)
    hipLaunchKernelGGL(cvt_xw, dim3(XBLK + WBLK), dim3(256), 0, stream, x, xb, W, wb);

    dim3 grid(CJ / 128, CK / 128, CB * CE);   // (4, 8, 128) = 4096 blocks
    hipLaunchKernelGGL(eg_kernel, grid, dim3(256), 0, stream, xb, Ind, wb, out);
}

// Round 6
// 469.528 us; speedup vs baseline: 1.0879x; 1.0084x over previous
//
#include <hip/hip_runtime.h>
#include <stdint.h>

typedef short short8 __attribute__((ext_vector_type(8)));
typedef float floatx16 __attribute__((ext_vector_type(16)));

// Problem constants
constexpr int CB = 8;      // batch
constexpr int CT = 8192;   // tokens
constexpr int CI = 512;    // in features (GEMM K-dim)
constexpr int CE = 16;     // experts
constexpr int CK = 1024;   // gathered rows per (b,e) (GEMM M-dim)
constexpr int CJ = 512;    // out features (GEMM N-dim)

// Device-global scratch.
// xb: x converted to bf16, [B][T][I] packed 2 elems/word  -> 64 MB
// wb: W pre-packed bf16 tiles [E][nt=4][kt=8][kpq=8][jn=128][q=4] -> 8 MB
__device__ uint32_t g_xb[(size_t)CB * CT * CI / 2];
__device__ uint32_t g_wb[(size_t)CE * CI * CJ / 2];

__device__ __forceinline__ uint32_t f2bf(float f) {
    union { float f; uint32_t u; } c; c.f = f;
    return (c.u + 0x7fffu + ((c.u >> 16) & 1u)) >> 16;   // RNE to bf16 bits
}
__device__ __forceinline__ uint32_t pack2(float lo, float hi) {
    return f2bf(lo) | (f2bf(hi) << 16);
}

__device__ __forceinline__ void gl_lds16(const uint32_t* g, uint32_t* l) {
    __builtin_amdgcn_global_load_lds(
        (const __attribute__((address_space(1))) uint32_t*)g,
        (__attribute__((address_space(3))) uint32_t*)l,
        16, 0, 0);
}

// ---- fused prologue: one launch converts x and W (unchanged from r5).
constexpr int XBLK = CB * CT * CI / 8 / 256;   // 16384
constexpr int WBLK = CE * CI * CJ / 8 / 256;   // 2048
__global__ __launch_bounds__(256) void cvt_xw(
    const float* __restrict__ x, uint32_t* __restrict__ xb,
    const float* __restrict__ W, uint32_t* __restrict__ wb)
{
    const int bid = blockIdx.x;
    if (bid < XBLK) {
        size_t i = (size_t)bid * 256 + threadIdx.x;      // one uint4 (8 floats)
        const float4* src = (const float4*)x;
        float4 a = src[2 * i], b = src[2 * i + 1];
        ((uint4*)xb)[i] = make_uint4(pack2(a.x, a.y), pack2(a.z, a.w),
                                     pack2(b.x, b.y), pack2(b.z, b.w));
    } else {
        uint32_t tid = (uint32_t)(bid - XBLK) * 256 + threadIdx.x;  // 524288 total
        int jn  = tid & 127;
        int kpq = (tid >> 7) & 7;
        int kt  = (tid >> 10) & 7;
        int nt  = (tid >> 13) & 3;
        int e   = tid >> 15;
        int n   = nt * 128 + jn;
        int k0  = kt * 64 + kpq * 8;
        const float* src = W + ((size_t)e * CI + k0) * CJ + n;
        uint4 o;
        o.x = pack2(src[0 * CJ], src[1 * CJ]);
        o.y = pack2(src[2 * CJ], src[3 * CJ]);
        o.z = pack2(src[4 * CJ], src[5 * CJ]);
        o.w = pack2(src[6 * CJ], src[7 * CJ]);
        ((uint4*)wb)[tid] = o;
    }
}

// ---- staging: 16 KB A tile + 16 KB B tile per kt (8 gl_lds16 per thread).
__device__ __forceinline__ void stage_tiles(const uint32_t* const* pA, const uint32_t* pB,
                                            int kt, uint32_t* As, uint32_t* Bs, int wv) {
    #pragma unroll
    for (int i = 0; i < 4; ++i)
        gl_lds16(pA[i] + kt * 32, &As[wv * 1024 + i * 256]);
    #pragma unroll
    for (int i = 0; i < 4; ++i)
        gl_lds16(pB + (size_t)kt * 4096 + i * 256, &Bs[wv * 1024 + i * 256]);
}

// ---- compute: four K=16 MFMA sub-steps on one staged K-tile.
__device__ __forceinline__ void compute_tile(const uint32_t* As, const uint32_t* Bs,
                                             int wm, int wn, int lrow, int lh,
                                             floatx16 acc[2][2]) {
    #pragma unroll
    for (int s = 0; s < 4; ++s) {
        short8 af[2], bfr[2];
        #pragma unroll
        for (int mt = 0; mt < 2; ++mt) {
            const int row = wm + mt * 32 + lrow;
            const int ch = (s * 2 + lh) ^ (lrow & 7);   // undo the A swizzle
            af[mt] = *(const short8*)&As[row * 32 + ch * 4];
        }
        #pragma unroll
        for (int nt = 0; nt < 2; ++nt) {
            const int jn = wn + nt * 32 + lrow;
            bfr[nt] = *(const short8*)&Bs[(s * 2 + lh) * 512 + jn * 4];
        }
        #pragma unroll
        for (int mt = 0; mt < 2; ++mt)
            #pragma unroll
            for (int nt = 0; nt < 2; ++nt)
                acc[mt][nt] = __builtin_amdgcn_mfma_f32_32x32x16_bf16(
                    af[mt], bfr[nt], acc[mt][nt], 0, 0, 0);
    }
}

__device__ __forceinline__ void fence_barrier() {
    __builtin_amdgcn_sched_barrier(0);
    __builtin_amdgcn_s_barrier();
    __builtin_amdgcn_sched_barrier(0);
}

// ---- main: 256 threads (4 waves), 128x128 tile, BK=64, 8 K-tiles.
// Double-buffered with COUNTED vmcnt(8): next-tile global_load_lds stay in
// flight across raw s_barriers (T4, m218). Each wave issues 8 loads/tile;
// after issuing tile kt+1's loads, vmcnt(8) == "tile kt's loads all landed".
// XCD swizzle (T1): grid flattened to 1D, id' = (id&7)*512 + id>>3 so the
// 4 ntile-blocks sharing an A panel + expert W co-locate per XCD (4096%8==0,
// bijective).
__global__ __launch_bounds__(256, 2) void eg_kernel(
    const uint32_t* __restrict__ xb, const int* __restrict__ Ind,
    const uint32_t* __restrict__ wb, float* __restrict__ out)
{
    __shared__ __align__(16) uint32_t As0[128 * 32], As1[128 * 32];  // 2 x 16 KB
    __shared__ __align__(16) uint32_t Bs0[32 * 128], Bs1[32 * 128];  // 2 x 16 KB
    __shared__ int s_idx[128];

    const int t = threadIdx.x;
    const uint32_t id2 = (blockIdx.x & 7) * 512 + (blockIdx.x >> 3);  // XCD swizzle
    const int ntile = id2 & 3;           // 0..3
    const int mtile = (id2 >> 2) & 7;    // 0..7
    const int z = id2 >> 5;              // b*E + e, 0..127
    const int e = z & (CE - 1);
    const int b = z >> 4;

    if (t < 128) s_idx[t] = Ind[z * CK + mtile * 128 + t];
    __syncthreads();

    const int ln = t & 63, wv = t >> 6;

    // A staging source: lane l stages 16B = global chunk ((l&7) ^ (l>>3)) of
    // gathered row (wv*32 + i*8 + (l>>3)); LDS dest linear (rule #21).
    const int sr = ln >> 3;
    const int gchunk = (ln & 7) ^ sr;
    const uint32_t* xb_b = xb + (size_t)b * CT * 256;    // 256 words per token row
    const uint32_t* pA[4];
    #pragma unroll
    for (int i = 0; i < 4; ++i) {
        int r = wv * 32 + i * 8 + sr;
        pA[i] = xb_b + (size_t)s_idx[r] * 256 + gchunk * 4;
    }
    // B staging source: contiguous pre-packed tile, linear copy.
    const uint32_t* pB = wb + ((size_t)(e * 4 + ntile) * 8) * 4096 + wv * 1024 + ln * 4;

    // compute-side lane mapping
    const int wm = (wv >> 1) * 64, wn = (wv & 1) * 64;
    const int lrow = ln & 31;
    const int lh = ln >> 5;

    const floatx16 fz = {0.f,0.f,0.f,0.f,0.f,0.f,0.f,0.f,0.f,0.f,0.f,0.f,0.f,0.f,0.f,0.f};
    floatx16 acc[2][2] = {{fz, fz}, {fz, fz}};

    stage_tiles(pA, pB, 0, As0, Bs0, wv);     // 8 loads in flight
    #pragma unroll
    for (int kt = 0; kt < 8; ++kt) {
        uint32_t* Acur = (kt & 1) ? As1 : As0;
        uint32_t* Bcur = (kt & 1) ? Bs1 : Bs0;
        uint32_t* Anxt = (kt & 1) ? As0 : As1;
        uint32_t* Bnxt = (kt & 1) ? Bs0 : Bs1;
        if (kt < 7) {
            stage_tiles(pA, pB, kt + 1, Anxt, Bnxt, wv);   // +8 in flight
            asm volatile("s_waitcnt vmcnt(8)" ::: "memory"); // cur's 8 landed
        } else {
            asm volatile("s_waitcnt vmcnt(0)" ::: "memory");
        }
        fence_barrier();                     // all waves: cur tile valid
        compute_tile(Acur, Bcur, wm, wn, lrow, lh, acc);
        if (kt < 7)
            fence_barrier();                 // all waves done reading cur
                                             // before next iter overwrites it
    }

    // ---- epilogue: C/D layout col=lane&31, row=(r&3)+8*(r>>2)+4*(lane>>5)
    const size_t obase = (size_t)z * CK * CJ;
    #pragma unroll
    for (int mt = 0; mt < 2; ++mt) {
        const int gm0 = mtile * 128 + wm + mt * 32 + lh * 4;
        #pragma unroll
        for (int nt = 0; nt < 2; ++nt) {
            const int gn = ntile * 128 + wn + nt * 32 + lrow;
            #pragma unroll
            for (int r = 0; r < 16; ++r) {
                const int gm = gm0 + (r & 3) + 8 * (r >> 2);
                out[obase + (size_t)gm * CJ + gn] = acc[mt][nt][r];
            }
        }
    }
}

extern "C" void kernel_launch(void* const* d_in, const int* in_sizes, int n_in,
                              void* d_out, int out_size, void* d_ws, size_t ws_size,
                              hipStream_t stream) {
    const float* x   = (const float*)d_in[0];
    const int*   Ind = (const int*)d_in[1];
    const float* W   = (const float*)d_in[2];
    float* out = (float*)d_out;

    uint32_t* xb; hipGetSymbolAddress((void**)&xb, HIP_SYMBOL(g_xb));
    uint32_t* wb; hipGetSymbolAddress((void**)&wb, HIP_SYMBOL(g_wb));

    // fused prologue: convert once per call (inputs may be re-poisoned)
    hipLaunchKernelGGL(cvt_xw, dim3(XBLK + WBLK), dim3(256), 0, stream, x, xb, W, wb);

    hipLaunchKernelGGL(eg_kernel, dim3(4096), dim3(256), 0, stream, xb, Ind, wb, out);
}

// Round 7
// 450.350 us; speedup vs baseline: 1.1342x; 1.0426x over previous
//
#include <hip/hip_runtime.h>
#include <stdint.h>

typedef short short8 __attribute__((ext_vector_type(8)));
typedef float floatx16 __attribute__((ext_vector_type(16)));

// Problem constants
constexpr int CB = 8;      // batch
constexpr int CT = 8192;   // tokens
constexpr int CI = 512;    // in features (GEMM K-dim)
constexpr int CE = 16;     // experts
constexpr int CK = 1024;   // gathered rows per (b,e) (GEMM M-dim)
constexpr int CJ = 512;    // out features (GEMM N-dim)

// Device-global scratch.
// xb: x converted to bf16, [B][T][I] packed 2 elems/word  -> 64 MB
// wb: W pre-packed bf16 tiles [E][nt=2][kt=8][kpg=8][n=256][q=4] -> 8 MB
__device__ uint32_t g_xb[(size_t)CB * CT * CI / 2];
__device__ uint32_t g_wb[(size_t)CE * CI * CJ / 2];

__device__ __forceinline__ uint32_t f2bf(float f) {
    union { float f; uint32_t u; } c; c.f = f;
    return (c.u + 0x7fffu + ((c.u >> 16) & 1u)) >> 16;   // RNE to bf16 bits
}
__device__ __forceinline__ uint32_t pack2(float lo, float hi) {
    return f2bf(lo) | (f2bf(hi) << 16);
}

__device__ __forceinline__ void gl_lds16(const uint32_t* g, uint32_t* l) {
    __builtin_amdgcn_global_load_lds(
        (const __attribute__((address_space(1))) uint32_t*)g,
        (__attribute__((address_space(3))) uint32_t*)l,
        16, 0, 0);
}

// ---- fused prologue: one launch converts x and W.
// blocks [0, XBLK): x fp32 -> bf16 (row layout, 2 elems/word, one uint4/thread)
// blocks [XBLK, XBLK+WBLK): W -> bf16 pre-packed LDS tile order:
//   word (e,nt,kt,kpg,n,q) = pack2(W[e][kt*64+kpg*8+2q][nt*256+n],
//                                  W[e][kt*64+kpg*8+2q+1][nt*256+n])
constexpr int XBLK = CB * CT * CI / 8 / 256;   // 16384
constexpr int WBLK = CE * CI * CJ / 8 / 256;   // 2048
__global__ __launch_bounds__(256) void cvt_xw(
    const float* __restrict__ x, uint32_t* __restrict__ xb,
    const float* __restrict__ W, uint32_t* __restrict__ wb)
{
    const int bid = blockIdx.x;
    if (bid < XBLK) {
        size_t i = (size_t)bid * 256 + threadIdx.x;      // one uint4 (8 floats)
        const float4* src = (const float4*)x;
        float4 a = src[2 * i], b = src[2 * i + 1];
        ((uint4*)xb)[i] = make_uint4(pack2(a.x, a.y), pack2(a.z, a.w),
                                     pack2(b.x, b.y), pack2(b.z, b.w));
    } else {
        uint32_t tid = (uint32_t)(bid - XBLK) * 256 + threadIdx.x;  // 524288 total
        int n   = tid & 255;
        int kpg = (tid >> 8) & 7;
        int kt  = (tid >> 11) & 7;
        int nt  = (tid >> 14) & 1;
        int e   = tid >> 15;
        int col = nt * 256 + n;
        int k0  = kt * 64 + kpg * 8;
        const float* src = W + ((size_t)e * CI + k0) * CJ + col;
        uint4 o;
        o.x = pack2(src[0 * CJ], src[1 * CJ]);
        o.y = pack2(src[2 * CJ], src[3 * CJ]);
        o.z = pack2(src[4 * CJ], src[5 * CJ]);
        o.w = pack2(src[6 * CJ], src[7 * CJ]);
        ((uint4*)wb)[tid] = o;
    }
}

// ---- staging: 32 KB A tile (256 rows x 64 k) + 32 KB B tile (64 k x 256 n)
// per kt; 8 waves, 8 gl_lds16 per thread (4 A + 4 B). LDS dests are
// wave-uniform-base + lane*16 (linear); A swizzle applied on global source.
__device__ __forceinline__ void stage_tiles(const uint32_t* const* pA, const uint32_t* pB,
                                            int kt, uint32_t* As, uint32_t* Bs,
                                            int wv, int ln) {
    #pragma unroll
    for (int i = 0; i < 4; ++i)
        gl_lds16(pA[i] + kt * 32, &As[(wv * 32 + i * 8) * 32 + ln * 4]);
    #pragma unroll
    for (int i = 0; i < 4; ++i)
        gl_lds16(pB + (size_t)kt * 8192 + i * 2048, &Bs[i * 2048 + wv * 256 + ln * 4]);
}

// ---- compute: four K=16 MFMA sub-steps; wave tile 128(M) x 64(N) = 4x2 frags.
__device__ __forceinline__ void compute_tile(const uint32_t* As, const uint32_t* Bs,
                                             int wm, int wn, int lrow, int lh,
                                             floatx16 acc[4][2]) {
    #pragma unroll
    for (int s = 0; s < 4; ++s) {
        short8 af[4], bfr[2];
        #pragma unroll
        for (int mt = 0; mt < 4; ++mt) {
            const int row = wm + mt * 32 + lrow;
            const int ch = (s * 2 + lh) ^ (lrow & 7);   // undo the A swizzle
            af[mt] = *(const short8*)&As[row * 32 + ch * 4];
        }
        #pragma unroll
        for (int nt = 0; nt < 2; ++nt) {
            const int jn = wn + nt * 32 + lrow;
            bfr[nt] = *(const short8*)&Bs[(s * 2 + lh) * 1024 + jn * 4];
        }
        #pragma unroll
        for (int mt = 0; mt < 4; ++mt)
            #pragma unroll
            for (int nt = 0; nt < 2; ++nt)
                acc[mt][nt] = __builtin_amdgcn_mfma_f32_32x32x16_bf16(
                    af[mt], bfr[nt], acc[mt][nt], 0, 0, 0);
    }
}

__device__ __forceinline__ void fence_barrier() {
    __builtin_amdgcn_sched_barrier(0);
    __builtin_amdgcn_s_barrier();
    __builtin_amdgcn_sched_barrier(0);
}

// ---- main: 512 threads (8 waves, 2M x 4N), 256x256 block tile, BK=64,
// 8 K-tiles, double-buffered with COUNTED vmcnt(8) (T4). LDS 128 KB ->
// 1 block/CU, 2 waves/SIMD. XCD swizzle: 1024 blocks, id'=(id&7)*128+id>>3.
__global__ __launch_bounds__(512, 2) void eg_kernel(
    const uint32_t* __restrict__ xb, const int* __restrict__ Ind,
    const uint32_t* __restrict__ wb, float* __restrict__ out)
{
    __shared__ __align__(16) uint32_t As0[256 * 32], As1[256 * 32];  // 2 x 32 KB
    __shared__ __align__(16) uint32_t Bs0[64 * 128], Bs1[64 * 128];  // 2 x 32 KB
    __shared__ int s_idx[256];

    const int t = threadIdx.x;
    const uint32_t id2 = (blockIdx.x & 7) * 128 + (blockIdx.x >> 3);  // XCD swizzle
    const int ntile = id2 & 1;           // 0..1
    const int mtile = (id2 >> 1) & 3;    // 0..3
    const int z = id2 >> 3;              // b*E + e, 0..127
    const int e = z & (CE - 1);
    const int b = z >> 4;

    if (t < 256) s_idx[t] = Ind[z * CK + mtile * 256 + t];
    __syncthreads();

    const int ln = t & 63, wv = t >> 6;

    // A staging source: wave wv stages rows [wv*32, wv*32+32). Lane l, load i:
    // row = wv*32 + i*8 + (l>>3); stages global chunk ((l&7) ^ (l>>3)) so LDS
    // position (l&7) holds chunk p^(row&7) (rule #21 involution).
    const int sr = ln >> 3;
    const int gchunk = (ln & 7) ^ sr;
    const uint32_t* xb_b = xb + (size_t)b * CT * 256;    // 256 words per token row
    const uint32_t* pA[4];
    #pragma unroll
    for (int i = 0; i < 4; ++i) {
        int r = wv * 32 + i * 8 + sr;
        pA[i] = xb_b + (size_t)s_idx[r] * 256 + gchunk * 4;
    }
    // B staging source: contiguous pre-packed (e,ntile) panel, linear copy.
    const uint32_t* pB = wb + (size_t)(e * 2 + ntile) * 65536 + t * 4;

    // compute-side lane mapping: wave grid 2M x 4N, wave tile 128 x 64
    const int wm = (wv >> 2) * 128, wn = (wv & 3) * 64;
    const int lrow = ln & 31;
    const int lh = ln >> 5;

    const floatx16 fz = {0.f,0.f,0.f,0.f,0.f,0.f,0.f,0.f,0.f,0.f,0.f,0.f,0.f,0.f,0.f,0.f};
    floatx16 acc[4][2] = {{fz, fz}, {fz, fz}, {fz, fz}, {fz, fz}};

    stage_tiles(pA, pB, 0, As0, Bs0, wv, ln);     // 8 loads in flight
    #pragma unroll
    for (int kt = 0; kt < 8; ++kt) {
        uint32_t* Acur = (kt & 1) ? As1 : As0;
        uint32_t* Bcur = (kt & 1) ? Bs1 : Bs0;
        uint32_t* Anxt = (kt & 1) ? As0 : As1;
        uint32_t* Bnxt = (kt & 1) ? Bs0 : Bs1;
        if (kt < 7) {
            stage_tiles(pA, pB, kt + 1, Anxt, Bnxt, wv, ln);  // +8 in flight
            asm volatile("s_waitcnt vmcnt(8)" ::: "memory");  // cur's 8 landed
        } else {
            asm volatile("s_waitcnt vmcnt(0)" ::: "memory");
        }
        fence_barrier();                     // all waves: cur tile valid
        compute_tile(Acur, Bcur, wm, wn, lrow, lh, acc);
        if (kt < 7)
            fence_barrier();                 // all waves done reading cur
    }

    // ---- epilogue: C/D layout col=lane&31, row=(r&3)+8*(r>>2)+4*(lane>>5)
    const size_t obase = (size_t)z * CK * CJ;
    #pragma unroll
    for (int mt = 0; mt < 4; ++mt) {
        const int gm0 = mtile * 256 + wm + mt * 32 + lh * 4;
        #pragma unroll
        for (int nt = 0; nt < 2; ++nt) {
            const int gn = ntile * 256 + wn + nt * 32 + lrow;
            #pragma unroll
            for (int r = 0; r < 16; ++r) {
                const int gm = gm0 + (r & 3) + 8 * (r >> 2);
                out[obase + (size_t)gm * CJ + gn] = acc[mt][nt][r];
            }
        }
    }
}

extern "C" void kernel_launch(void* const* d_in, const int* in_sizes, int n_in,
                              void* d_out, int out_size, void* d_ws, size_t ws_size,
                              hipStream_t stream) {
    const float* x   = (const float*)d_in[0];
    const int*   Ind = (const int*)d_in[1];
    const float* W   = (const float*)d_in[2];
    float* out = (float*)d_out;

    uint32_t* xb; hipGetSymbolAddress((void**)&xb, HIP_SYMBOL(g_xb));
    uint32_t* wb; hipGetSymbolAddress((void**)&wb, HIP_SYMBOL(g_wb));

    // fused prologue: convert once per call (inputs may be re-poisoned)
    hipLaunchKernelGGL(cvt_xw, dim3(XBLK + WBLK), dim3(256), 0, stream, x, xb, W, wb);

    // grid: 2 ntiles x 4 mtiles x 128 z = 1024 blocks, flattened for swizzle
    hipLaunchKernelGGL(eg_kernel, dim3(1024), dim3(512), 0, stream, xb, Ind, wb, out);
}